// Round 4
// baseline (1285.347 us; speedup 1.0000x reference)
//
#include <hip/hip_runtime.h>
#include <hip/hip_bf16.h>
#include <cstdio>

// Problem dims
#define BS   2
#define LL   2048
#define HH   8
#define PP   64
#define NQ   300          // d_state / num queries
#define NPAD 320          // padded n (16B-aligned slices of 20)
#define SLICE 20          // per-wave n-slice (8 waves * 20 = 160 per block, 2 blocks cover 320)
#define TT   128          // chunk length
#define NCH  16           // L / TT
#define DI   512
#define DKEY 1034

// ---------------------------------------------------------------------------
// Generic GEMM-NT: C[m,n] = sum_k A[m*lda+k] * B[n*ldb+k]  (64x64 tile)
// ---------------------------------------------------------------------------
__global__ __launch_bounds__(256) void gemm_nt(
    const float* __restrict__ A, const float* __restrict__ Bm, float* __restrict__ C,
    int M, int N, int K, int lda, int ldb, int ldc)
{
    __shared__ float As[16][68];
    __shared__ float Bs[16][68];
    const int tid = threadIdx.x;
    const int tx = tid & 15, ty = tid >> 4;
    const int m0 = blockIdx.x * 64, n0 = blockIdx.y * 64;
    const int lr = tid >> 2, lk = (tid & 3) << 2;
    float acc[4][4] = {};
    for (int k0 = 0; k0 < K; k0 += 16) {
        float4 av = make_float4(0.f,0.f,0.f,0.f), bv = make_float4(0.f,0.f,0.f,0.f);
        int am = m0 + lr;
        if (am < M) av = *(const float4*)(A + (size_t)am * lda + k0 + lk);
        int bn = n0 + lr;
        if (bn < N) bv = *(const float4*)(Bm + (size_t)bn * ldb + k0 + lk);
        __syncthreads();
        As[lk+0][lr] = av.x; As[lk+1][lr] = av.y; As[lk+2][lr] = av.z; As[lk+3][lr] = av.w;
        Bs[lk+0][lr] = bv.x; Bs[lk+1][lr] = bv.y; Bs[lk+2][lr] = bv.z; Bs[lk+3][lr] = bv.w;
        __syncthreads();
        #pragma unroll
        for (int kk = 0; kk < 16; ++kk) {
            float a0 = As[kk][ty*4+0], a1 = As[kk][ty*4+1], a2 = As[kk][ty*4+2], a3 = As[kk][ty*4+3];
            float b0 = Bs[kk][tx*4+0], b1 = Bs[kk][tx*4+1], b2 = Bs[kk][tx*4+2], b3 = Bs[kk][tx*4+3];
            acc[0][0] = fmaf(a0,b0,acc[0][0]); acc[0][1] = fmaf(a0,b1,acc[0][1]);
            acc[0][2] = fmaf(a0,b2,acc[0][2]); acc[0][3] = fmaf(a0,b3,acc[0][3]);
            acc[1][0] = fmaf(a1,b0,acc[1][0]); acc[1][1] = fmaf(a1,b1,acc[1][1]);
            acc[1][2] = fmaf(a1,b2,acc[1][2]); acc[1][3] = fmaf(a1,b3,acc[1][3]);
            acc[2][0] = fmaf(a2,b0,acc[2][0]); acc[2][1] = fmaf(a2,b1,acc[2][1]);
            acc[2][2] = fmaf(a2,b2,acc[2][2]); acc[2][3] = fmaf(a2,b3,acc[2][3]);
            acc[3][0] = fmaf(a3,b0,acc[3][0]); acc[3][1] = fmaf(a3,b1,acc[3][1]);
            acc[3][2] = fmaf(a3,b2,acc[3][2]); acc[3][3] = fmaf(a3,b3,acc[3][3]);
        }
    }
    #pragma unroll
    for (int i = 0; i < 4; ++i) {
        int m = m0 + ty*4 + i;
        if (m >= M) continue;
        #pragma unroll
        for (int j = 0; j < 4; ++j) {
            int n = n0 + tx*4 + j;
            if (n < N) C[(size_t)m * ldc + n] = acc[i][j];
        }
    }
}

// ---------------------------------------------------------------------------
// Bigger GEMM-NT: 128x64 tile, 256 threads, 8x4 micro-tile (VALU-dominant).
// ---------------------------------------------------------------------------
__global__ __launch_bounds__(256) void gemm_nt_big(
    const float* __restrict__ A, const float* __restrict__ Bm, float* __restrict__ C,
    int M, int N, int K, int lda, int ldb, int ldc)
{
    __shared__ float As[16][132];
    __shared__ float Bs[16][68];
    const int tid = threadIdx.x;
    const int tx = tid & 15, ty = tid >> 4;
    const int m0 = blockIdx.x * 128, n0 = blockIdx.y * 64;
    const int lr = tid >> 2, lk = (tid & 3) << 2;
    float acc[8][4] = {};
    for (int k0 = 0; k0 < K; k0 += 16) {
        float4 a0v = make_float4(0.f,0.f,0.f,0.f), a1v = a0v, bv = a0v;
        int am0 = m0 + lr, am1 = m0 + 64 + lr;
        if (am0 < M) a0v = *(const float4*)(A + (size_t)am0 * lda + k0 + lk);
        if (am1 < M) a1v = *(const float4*)(A + (size_t)am1 * lda + k0 + lk);
        int bn = n0 + lr;
        if (bn < N) bv = *(const float4*)(Bm + (size_t)bn * ldb + k0 + lk);
        __syncthreads();
        As[lk+0][lr] = a0v.x; As[lk+1][lr] = a0v.y; As[lk+2][lr] = a0v.z; As[lk+3][lr] = a0v.w;
        As[lk+0][64+lr] = a1v.x; As[lk+1][64+lr] = a1v.y; As[lk+2][64+lr] = a1v.z; As[lk+3][64+lr] = a1v.w;
        Bs[lk+0][lr] = bv.x; Bs[lk+1][lr] = bv.y; Bs[lk+2][lr] = bv.z; Bs[lk+3][lr] = bv.w;
        __syncthreads();
        #pragma unroll
        for (int kk = 0; kk < 16; ++kk) {
            float a[8], b[4];
            #pragma unroll
            for (int i = 0; i < 8; ++i) a[i] = As[kk][ty*8+i];
            #pragma unroll
            for (int j = 0; j < 4; ++j) b[j] = Bs[kk][tx*4+j];
            #pragma unroll
            for (int i = 0; i < 8; ++i)
                #pragma unroll
                for (int j = 0; j < 4; ++j)
                    acc[i][j] = fmaf(a[i], b[j], acc[i][j]);
        }
    }
    #pragma unroll
    for (int i = 0; i < 8; ++i) {
        int m = m0 + ty*8 + i;
        if (m >= M) continue;
        #pragma unroll
        for (int j = 0; j < 4; ++j) {
            int n = n0 + tx*4 + j;
            if (n < N) C[(size_t)m * ldc + n] = acc[i][j];
        }
    }
}

// ---------------------------------------------------------------------------
// dt / B / C precompute. Writes packed coefficient pairs {a=exp(dt*A), u=dt*B}
// per (b,h,l,n) and C per (b,l,n), both padded to NPAD (pads: a=1,u=0,c=0).
// ---------------------------------------------------------------------------
__global__ __launch_bounds__(256) void dtbc_kernel(
    const float* __restrict__ dist, const float* __restrict__ zx,
    const float* __restrict__ W_bc, const float* __restrict__ W_dt,
    const float* __restrict__ dt_bias, const float* __restrict__ A_log,
    float2* __restrict__ pairs, float* __restrict__ Cc)
{
    const int r = blockIdx.x;           // b*LL + l
    const int b = r >> 11, l = r & 2047;
    const int tid = threadIdx.x;
    const float bb = zx[(size_t)r*DKEY + 1024];
    const float cb = zx[(size_t)r*DKEY + 1025];
    #pragma unroll
    for (int rep = 0; rep < 2; ++rep) {
        int n = rep*256 + tid;
        if (n >= NPAD) continue;
        if (n < NQ) {
            const float4* dp = (const float4*)(dist + ((size_t)r*NQ + n)*16);
            float d[16];
            #pragma unroll
            for (int j = 0; j < 4; ++j) {
                float4 v = dp[j];
                d[4*j+0]=v.x; d[4*j+1]=v.y; d[4*j+2]=v.z; d[4*j+3]=v.w;
            }
            float Bv = bb, Cv = cb;
            #pragma unroll
            for (int j = 0; j < 16; ++j) {
                Bv = fmaf(d[j], W_bc[j],     Bv);
                Cv = fmaf(d[j], W_bc[16+j],  Cv);
            }
            Cc[(size_t)r*NPAD + n] = Cv;
            #pragma unroll
            for (int h = 0; h < HH; ++h) {
                float s = zx[(size_t)r*DKEY + 1026 + h] + dt_bias[h];
                #pragma unroll
                for (int j = 0; j < 16; ++j) s = fmaf(d[j], W_dt[h*16+j], s);
                float dtv = (s > 20.f) ? s : log1pf(expf(s));
                float Ah = -expf(A_log[h]);
                pairs[((size_t)(b*HH+h)*LL + l)*NPAD + n] = make_float2(expf(dtv*Ah), dtv*Bv);
            }
        } else {
            Cc[(size_t)r*NPAD + n] = 0.f;
            #pragma unroll
            for (int h = 0; h < HH; ++h)
                pairs[((size_t)(b*HH+h)*LL + l)*NPAD + n] = make_float2(1.f, 0.f);
        }
    }
}

// ---------------------------------------------------------------------------
// Quarter-chunk decay products: Adec4[bh][c][q][n] = prod over 32 steps.
// ---------------------------------------------------------------------------
__global__ __launch_bounds__(320) void adec_kernel(
    const float2* __restrict__ pairs, float* __restrict__ Adec4)
{
    const int bid = blockIdx.x;        // q + 4*(c + 16*bh)
    const int q = bid & 3, c = (bid >> 2) & 15, bh = bid >> 6;
    const int n = threadIdx.x;
    const float2* pr = pairs + ((size_t)bh*LL + c*TT + q*32)*NPAD + n;
    float prod = 1.f;
    #pragma unroll 8
    for (int t = 0; t < 32; ++t) prod *= pr[(size_t)t*NPAD].x;
    Adec4[(((size_t)bh*NCH + c)*4 + q)*NPAD + n] = prod;
}

// ---------------------------------------------------------------------------
// Sweep A: intra-chunk scan from zero state. block = (dir,b,h,chunk,nhalf),
// 512 thr. Wave w owns n in [nh*160 + w*20, +20); lane = p.
// Coefficients loaded via VECTOR loads with a runtime-zero VGPR offset
// (izero*tid) so the compiler cannot scalarize them to s_load: all 64 lanes
// hit the same address -> single broadcast transaction, vmcnt-pipelined.
// ---------------------------------------------------------------------------
__global__ __launch_bounds__(512, 4) void sweepA(
    const float2* __restrict__ pairs, const float* __restrict__ Cc,
    const float* __restrict__ zx,
    float* __restrict__ Sloc,
    float* __restrict__ y00, float* __restrict__ y01,
    float* __restrict__ y10, float* __restrict__ y11, int izero)
{
    const int bid = blockIdx.x;
    const int nh = bid & 1, c = (bid >> 1) & 15, h = (bid >> 5) & 7;
    const int b = (bid >> 8) & 1, dir = bid >> 9;
    const int tid = threadIdx.x;
    const int p = tid & 63;
    const int w = tid >> 6;
    const int n0 = nh*160 + w*SLICE;
    const size_t zoff = (size_t)(izero * (int)tid);   // runtime 0, defeats scalarization
    float* __restrict__ ybuf = dir ? (nh ? y11 : y10) : (nh ? y01 : y00);

    __shared__ float yred[8*512];

    float S[SLICE];
    #pragma unroll
    for (int i = 0; i < SLICE; ++i) S[i] = 0.f;

    const size_t prow = (size_t)(b*HH + h) * LL;

    for (int t8 = 0; t8 < NCH; ++t8) {
        #pragma unroll
        for (int tt = 0; tt < 8; ++tt) {
            const int t  = t8*8 + tt;
            const int ls = c*TT + t;
            const int l  = dir ? (LL-1-ls) : ls;
            const float4* __restrict__ pr4 =
                (const float4*)(pairs + (prow + l)*NPAD + n0 + zoff);
            const float4* __restrict__ cw4 =
                (const float4*)(Cc + ((size_t)(b*LL + l)*NPAD) + n0 + zoff);
            const float xp = zx[(size_t)(b*LL + l)*DKEY + 512 + h*PP + p];
            float4 cv[5];
            #pragma unroll
            for (int k = 0; k < 5; ++k) cv[k] = cw4[k];
            float yp = 0.f;
            #pragma unroll
            for (int k = 0; k < 10; ++k) {
                float4 pv = pr4[k];     // {a0,u0,a1,u1} for n = n0+2k, n0+2k+1
                float c0 = (&cv[k>>1].x)[(k&1)*2];
                float c1 = (&cv[k>>1].x)[(k&1)*2+1];
                S[2*k]   = fmaf(S[2*k],   pv.x, pv.y * xp);
                yp = fmaf(S[2*k],   c0, yp);
                S[2*k+1] = fmaf(S[2*k+1], pv.z, pv.w * xp);
                yp = fmaf(S[2*k+1], c1, yp);
            }
            yred[tt*512 + tid] = yp;
        }
        __syncthreads();
        {
            int sl = tid >> 6, pp2 = tid & 63;
            float sum = 0.f;
            #pragma unroll
            for (int wv = 0; wv < 8; ++wv) sum += yred[sl*512 + wv*64 + pp2];
            int ls2 = c*TT + t8*8 + sl;
            int l2  = dir ? (LL-1-ls2) : ls2;
            ybuf[((size_t)(b*LL + l2)*HH + h)*PP + pp2] = sum;
        }
        __syncthreads();
    }
    // chunk-end state
    const size_t sbase = (((size_t)((dir*BS + b)*HH + h)*NCH + c)*NQ)*PP;
    #pragma unroll
    for (int i = 0; i < SLICE; ++i) {
        int n = n0 + i;
        if (n < NQ) Sloc[sbase + (size_t)n*PP + p] = S[i];
    }
}

// ---------------------------------------------------------------------------
// Inter-chunk scan: carry[c] = state before chunk c; carry[NCH] = final state.
// ---------------------------------------------------------------------------
__global__ __launch_bounds__(256) void chunkscan(
    const float* __restrict__ Sloc, const float* __restrict__ Adec4,
    const float* __restrict__ proj, float* __restrict__ carry)
{
    const int bid = blockIdx.x;          // 2400 = 32 * 75
    const int dbh = bid / 75;            // dir*16 + b*8 + h
    const int tile = bid % 75;
    const int e = tile*256 + threadIdx.x;   // < 19200
    const int n = e >> 6, p = e & 63;
    const int h = dbh & 7, b = (dbh >> 3) & 1, dir = dbh >> 4;
    const int bh = dbh & 15;
    float cur = proj[((size_t)(b*NQ + n))*DI + h*PP + p];   // init state
    const size_t cbase = (size_t)dbh * (NCH+1) * NQ * PP;
    const size_t sbase = (size_t)dbh * NCH * NQ * PP;
    carry[cbase + e] = cur;
    #pragma unroll
    for (int cc = 0; cc < NCH; ++cc) {
        int cF = dir ? (NCH-1-cc) : cc;
        const float* a4 = Adec4 + (((size_t)bh*NCH + cF)*4)*NPAD + n;
        float ad = a4[0] * a4[NPAD] * a4[2*NPAD] * a4[3*NPAD];
        cur = fmaf(cur, ad, Sloc[sbase + (size_t)cc*NQ*PP + e]);
        carry[cbase + (size_t)(cc+1)*NQ*PP + e] = cur;
    }
}

// ---------------------------------------------------------------------------
// Sweep B: y += sum_n C[l,n]*beta[l,n]*carry[n,p], beta folded into cr regs.
// Same vector-broadcast load scheme as sweepA.
// ---------------------------------------------------------------------------
__global__ __launch_bounds__(512, 4) void sweepB(
    const float2* __restrict__ pairs, const float* __restrict__ Cc,
    const float* __restrict__ carry,
    float* __restrict__ y00, float* __restrict__ y01,
    float* __restrict__ y10, float* __restrict__ y11, int izero)
{
    const int bid = blockIdx.x;
    const int nh = bid & 1, c = (bid >> 1) & 15, h = (bid >> 5) & 7;
    const int b = (bid >> 8) & 1, dir = bid >> 9;
    const int tid = threadIdx.x;
    const int p = tid & 63;
    const int w = tid >> 6;
    const int n0 = nh*160 + w*SLICE;
    const size_t zoff = (size_t)(izero * (int)tid);
    float* __restrict__ ybuf = dir ? (nh ? y11 : y10) : (nh ? y01 : y00);

    __shared__ float yred[8*512];

    const size_t cbase = (((size_t)((dir*BS + b)*HH + h)*(NCH+1) + c)*NQ)*PP;
    float cr[SLICE];
    #pragma unroll
    for (int i = 0; i < SLICE; ++i) {
        int n = n0 + i;
        cr[i] = (n < NQ) ? carry[cbase + (size_t)n*PP + p] : 0.f;
    }

    const size_t prow = (size_t)(b*HH + h) * LL;

    for (int t8 = 0; t8 < NCH; ++t8) {
        #pragma unroll
        for (int tt = 0; tt < 8; ++tt) {
            const int t  = t8*8 + tt;
            const int ls = c*TT + t;
            const int l  = dir ? (LL-1-ls) : ls;
            const float4* __restrict__ pr4 =
                (const float4*)(pairs + (prow + l)*NPAD + n0 + zoff);
            const float4* __restrict__ cw4 =
                (const float4*)(Cc + ((size_t)(b*LL + l)*NPAD) + n0 + zoff);
            float4 cv[5];
            #pragma unroll
            for (int k = 0; k < 5; ++k) cv[k] = cw4[k];
            float yc = 0.f;
            #pragma unroll
            for (int k = 0; k < 10; ++k) {
                float4 pv = pr4[k];
                float c0 = (&cv[k>>1].x)[(k&1)*2];
                float c1 = (&cv[k>>1].x)[(k&1)*2+1];
                cr[2*k]   *= pv.x;
                yc = fmaf(cr[2*k],   c0, yc);
                cr[2*k+1] *= pv.z;
                yc = fmaf(cr[2*k+1], c1, yc);
            }
            yred[tt*512 + tid] = yc;
        }
        __syncthreads();
        {
            int sl = tid >> 6, pp2 = tid & 63;
            float sum = 0.f;
            #pragma unroll
            for (int wv = 0; wv < 8; ++wv) sum += yred[sl*512 + wv*64 + pp2];
            int ls2 = c*TT + t8*8 + sl;
            int l2  = dir ? (LL-1-ls2) : ls2;
            size_t yi = ((size_t)(b*LL + l2)*HH + h)*PP + pp2;
            ybuf[yi] += sum;
        }
        __syncthreads();
    }
}

// ---------------------------------------------------------------------------
// Gated RMSNorm over 4 y-partials.
// ---------------------------------------------------------------------------
__global__ __launch_bounds__(256) void gate_rms(
    const float* __restrict__ zx,
    const float* __restrict__ y00, const float* __restrict__ y01,
    const float* __restrict__ y10, const float* __restrict__ y11,
    const float* __restrict__ Dp,
    const float* __restrict__ knw, float* __restrict__ kfn)
{
    const int r = blockIdx.x, tid = threadIdx.x;
    __shared__ float part[4];
    float g[2];
    #pragma unroll
    for (int rep = 0; rep < 2; ++rep) {
        int dcol = rep*256 + tid;
        size_t yi = (size_t)r*DI + dcol;
        float zv = zx[(size_t)r*DKEY + dcol];
        float xv = zx[(size_t)r*DKEY + 512 + dcol];
        float yv = 0.5f*(y00[yi] + y01[yi] + y10[yi] + y11[yi]) + xv * Dp[dcol >> 6];
        float sig = 1.f / (1.f + expf(-zv));
        g[rep] = yv * (zv * sig);
    }
    float ss = g[0]*g[0] + g[1]*g[1];
    #pragma unroll
    for (int o = 32; o; o >>= 1) ss += __shfl_xor(ss, o, 64);
    if ((tid & 63) == 0) part[tid >> 6] = ss;
    __syncthreads();
    float tot = part[0] + part[1] + part[2] + part[3];
    float scale = rsqrtf(tot * (1.f/512.f) + 1e-5f);
    #pragma unroll
    for (int rep = 0; rep < 2; ++rep) {
        int dcol = rep*256 + tid;
        kfn[(size_t)r*DI + dcol] = g[rep] * scale * knw[dcol];
    }
}

// ---------------------------------------------------------------------------
// Final-state LayerNorm: lastn[b,q,(h,p)] from 0.5*(Sf+Sb)
// ---------------------------------------------------------------------------
__global__ __launch_bounds__(512) void state_ln(
    const float* __restrict__ carry, const float* __restrict__ qw,
    const float* __restrict__ qb, float* __restrict__ lastn)
{
    const int row = blockIdx.x;          // b*NQ + q
    const int b = row / NQ, q = row % NQ;
    const int tid = threadIdx.x;         // 512
    const int h = tid >> 6, p = tid & 63;
    __shared__ float pm[8], pv[8];
    size_t iF = ((((size_t)((0*BS + b)*HH + h))*(NCH+1) + NCH)*NQ + q)*PP + p;
    size_t iB = ((((size_t)((1*BS + b)*HH + h))*(NCH+1) + NCH)*NQ + q)*PP + p;
    float v = 0.5f * (carry[iF] + carry[iB]);
    float s1 = v, s2 = v*v;
    #pragma unroll
    for (int o = 32; o; o >>= 1) { s1 += __shfl_xor(s1, o, 64); s2 += __shfl_xor(s2, o, 64); }
    if ((tid & 63) == 0) { pm[tid >> 6] = s1; pv[tid >> 6] = s2; }
    __syncthreads();
    float m = 0.f, s = 0.f;
    #pragma unroll
    for (int i = 0; i < 8; ++i) { m += pm[i]; s += pv[i]; }
    m *= (1.f/512.f);
    s = s*(1.f/512.f) - m*m;
    lastn[(size_t)row*DI + tid] = (v - m)*rsqrtf(s + 1e-5f)*qw[tid] + qb[tid];
}

// ---------------------------------------------------------------------------
extern "C" void kernel_launch(void* const* d_in, const int* in_sizes, int n_in,
                              void* d_out, int out_size, void* d_ws, size_t ws_size,
                              hipStream_t stream)
{
    const float* in_key    = (const float*)d_in[0];
    const float* in_query  = (const float*)d_in[1];
    const float* dist      = (const float*)d_in[2];
    const float* W_key     = (const float*)d_in[3];
    const float* W_query   = (const float*)d_in[4];
    const float* W_bc      = (const float*)d_in[5];
    const float* W_dt      = (const float*)d_in[6];
    const float* dt_bias   = (const float*)d_in[7];
    const float* A_log     = (const float*)d_in[8];
    const float* Dp        = (const float*)d_in[9];
    const float* W_out_key = (const float*)d_in[10];
    const float* W_out_qry = (const float*)d_in[11];
    const float* knw       = (const float*)d_in[12];
    const float* qw        = (const float*)d_in[13];
    const float* qb        = (const float*)d_in[14];
    float* out = (float*)d_out;

    float* ws = (float*)d_ws;
    size_t off = 0;
    auto alloc = [&](size_t nf) { float* pp = ws + off; off += nf; return pp; };
    float*  zx    = alloc((size_t)4096*DKEY);             // 4.24M
    float*  proj  = alloc((size_t)600*DI);                // 0.31M
    float2* pairs = (float2*)alloc((size_t)16*LL*NPAD*2); // 21.0M floats
    float*  Cc    = alloc((size_t)BS*LL*NPAD);            // 1.31M
    float*  Sloc  = alloc((size_t)32*NCH*NQ*PP);          // 9.83M (reused for kfn/lastn)
    float*  Adec4 = alloc((size_t)16*NCH*4*NPAD);         // 0.33M
    float*  carry = alloc((size_t)32*(NCH+1)*NQ*PP);      // 10.4M
    float*  y00   = alloc((size_t)BS*LL*DI);              // 2.1M
    float*  y01   = alloc((size_t)BS*LL*DI);              // 2.1M
    float*  y10   = alloc((size_t)BS*LL*DI);              // 2.1M
    float*  y11   = alloc((size_t)BS*LL*DI);              // 2.1M
    float*  kfn   = Sloc;                                  // alias (dead after chunkscan)
    float*  lastn = Sloc + (size_t)4096*DI;
    if (off * sizeof(float) > ws_size) {
        fprintf(stderr, "kernel_launch: workspace too small: need %zu bytes, have %zu\n",
                off * sizeof(float), ws_size);
        return;
    }

    dim3 blk(256);
    // K1: zxbcdt = in_key @ W_key^T   [4096 x 1034]
    gemm_nt_big<<<dim3(32, 17), blk, 0, stream>>>(in_key, W_key, zx, 4096, DKEY, 256, 256, 256, DKEY);
    // K2: init = in_query @ W_query^T  [600 x 512]
    gemm_nt<<<dim3(10, 8), blk, 0, stream>>>(in_query, W_query, proj, 600, DI, 256, 256, 256, DI);
    // K3: coefficient precompute
    dtbc_kernel<<<4096, blk, 0, stream>>>(dist, zx, W_bc, W_dt, dt_bias, A_log, pairs, Cc);
    // K3b: quarter-chunk decay products (dir-shared)
    adec_kernel<<<1024, dim3(320), 0, stream>>>(pairs, Adec4);
    // K4: intra-chunk scans (both directions, n-split)
    sweepA<<<1024, dim3(512), 0, stream>>>(pairs, Cc, zx, Sloc, y00, y01, y10, y11, 0);
    // K5: inter-chunk scan
    chunkscan<<<2400, blk, 0, stream>>>(Sloc, Adec4, proj, carry);
    // K6: carry corrections into y
    sweepB<<<1024, dim3(512), 0, stream>>>(pairs, Cc, carry, y00, y01, y10, y11, 0);
    // K7: gated RMSNorm + out_key projection
    gate_rms<<<4096, blk, 0, stream>>>(zx, y00, y01, y10, y11, Dp, knw, kfn);
    gemm_nt<<<dim3(64, 4), blk, 0, stream>>>(kfn, W_out_key, out, 4096, 256, DI, DI, DI, 256);
    // K8: final-state LayerNorm + out_query projection
    state_ln<<<600, dim3(512), 0, stream>>>(carry, qw, qb, lastn);
    gemm_nt<<<dim3(10, 4), blk, 0, stream>>>(lastn, W_out_qry, out + (size_t)4096*256, 600, 256, DI, DI, DI, 256);
}

// Round 5
// 1234.635 us; speedup vs baseline: 1.0411x; 1.0411x over previous
//
#include <hip/hip_runtime.h>
#include <hip/hip_bf16.h>
#include <cstdio>

// Problem dims
#define BS   2
#define LL   2048
#define HH   8
#define PP   64
#define NQ   300          // d_state / num queries
#define NPAD 320          // padded n
#define SLICE 10          // per-wave n-slice per pass (8 waves * 10 = 80; 4 passes = 320)
#define NPASS 4
#define TT   128          // chunk length
#define NCH  16           // L / TT
#define DI   512
#define DKEY 1034

// ---------------------------------------------------------------------------
// Generic GEMM-NT: C[m,n] = sum_k A[m*lda+k] * B[n*ldb+k]  (64x64 tile)
// ---------------------------------------------------------------------------
__global__ __launch_bounds__(256) void gemm_nt(
    const float* __restrict__ A, const float* __restrict__ Bm, float* __restrict__ C,
    int M, int N, int K, int lda, int ldb, int ldc)
{
    __shared__ float As[16][68];
    __shared__ float Bs[16][68];
    const int tid = threadIdx.x;
    const int tx = tid & 15, ty = tid >> 4;
    const int m0 = blockIdx.x * 64, n0 = blockIdx.y * 64;
    const int lr = tid >> 2, lk = (tid & 3) << 2;
    float acc[4][4] = {};
    for (int k0 = 0; k0 < K; k0 += 16) {
        float4 av = make_float4(0.f,0.f,0.f,0.f), bv = make_float4(0.f,0.f,0.f,0.f);
        int am = m0 + lr;
        if (am < M) av = *(const float4*)(A + (size_t)am * lda + k0 + lk);
        int bn = n0 + lr;
        if (bn < N) bv = *(const float4*)(Bm + (size_t)bn * ldb + k0 + lk);
        __syncthreads();
        As[lk+0][lr] = av.x; As[lk+1][lr] = av.y; As[lk+2][lr] = av.z; As[lk+3][lr] = av.w;
        Bs[lk+0][lr] = bv.x; Bs[lk+1][lr] = bv.y; Bs[lk+2][lr] = bv.z; Bs[lk+3][lr] = bv.w;
        __syncthreads();
        #pragma unroll
        for (int kk = 0; kk < 16; ++kk) {
            float a0 = As[kk][ty*4+0], a1 = As[kk][ty*4+1], a2 = As[kk][ty*4+2], a3 = As[kk][ty*4+3];
            float b0 = Bs[kk][tx*4+0], b1 = Bs[kk][tx*4+1], b2 = Bs[kk][tx*4+2], b3 = Bs[kk][tx*4+3];
            acc[0][0] = fmaf(a0,b0,acc[0][0]); acc[0][1] = fmaf(a0,b1,acc[0][1]);
            acc[0][2] = fmaf(a0,b2,acc[0][2]); acc[0][3] = fmaf(a0,b3,acc[0][3]);
            acc[1][0] = fmaf(a1,b0,acc[1][0]); acc[1][1] = fmaf(a1,b1,acc[1][1]);
            acc[1][2] = fmaf(a1,b2,acc[1][2]); acc[1][3] = fmaf(a1,b3,acc[1][3]);
            acc[2][0] = fmaf(a2,b0,acc[2][0]); acc[2][1] = fmaf(a2,b1,acc[2][1]);
            acc[2][2] = fmaf(a2,b2,acc[2][2]); acc[2][3] = fmaf(a2,b3,acc[2][3]);
            acc[3][0] = fmaf(a3,b0,acc[3][0]); acc[3][1] = fmaf(a3,b1,acc[3][1]);
            acc[3][2] = fmaf(a3,b2,acc[3][2]); acc[3][3] = fmaf(a3,b3,acc[3][3]);
        }
    }
    #pragma unroll
    for (int i = 0; i < 4; ++i) {
        int m = m0 + ty*4 + i;
        if (m >= M) continue;
        #pragma unroll
        for (int j = 0; j < 4; ++j) {
            int n = n0 + tx*4 + j;
            if (n < N) C[(size_t)m * ldc + n] = acc[i][j];
        }
    }
}

// ---------------------------------------------------------------------------
// Bigger GEMM-NT: 128x64 tile, 256 threads, 8x4 micro-tile.
// ---------------------------------------------------------------------------
__global__ __launch_bounds__(256) void gemm_nt_big(
    const float* __restrict__ A, const float* __restrict__ Bm, float* __restrict__ C,
    int M, int N, int K, int lda, int ldb, int ldc)
{
    __shared__ float As[16][132];
    __shared__ float Bs[16][68];
    const int tid = threadIdx.x;
    const int tx = tid & 15, ty = tid >> 4;
    const int m0 = blockIdx.x * 128, n0 = blockIdx.y * 64;
    const int lr = tid >> 2, lk = (tid & 3) << 2;
    float acc[8][4] = {};
    for (int k0 = 0; k0 < K; k0 += 16) {
        float4 a0v = make_float4(0.f,0.f,0.f,0.f), a1v = a0v, bv = a0v;
        int am0 = m0 + lr, am1 = m0 + 64 + lr;
        if (am0 < M) a0v = *(const float4*)(A + (size_t)am0 * lda + k0 + lk);
        if (am1 < M) a1v = *(const float4*)(A + (size_t)am1 * lda + k0 + lk);
        int bn = n0 + lr;
        if (bn < N) bv = *(const float4*)(Bm + (size_t)bn * ldb + k0 + lk);
        __syncthreads();
        As[lk+0][lr] = a0v.x; As[lk+1][lr] = a0v.y; As[lk+2][lr] = a0v.z; As[lk+3][lr] = a0v.w;
        As[lk+0][64+lr] = a1v.x; As[lk+1][64+lr] = a1v.y; As[lk+2][64+lr] = a1v.z; As[lk+3][64+lr] = a1v.w;
        Bs[lk+0][lr] = bv.x; Bs[lk+1][lr] = bv.y; Bs[lk+2][lr] = bv.z; Bs[lk+3][lr] = bv.w;
        __syncthreads();
        #pragma unroll
        for (int kk = 0; kk < 16; ++kk) {
            float a[8], b[4];
            #pragma unroll
            for (int i = 0; i < 8; ++i) a[i] = As[kk][ty*8+i];
            #pragma unroll
            for (int j = 0; j < 4; ++j) b[j] = Bs[kk][tx*4+j];
            #pragma unroll
            for (int i = 0; i < 8; ++i)
                #pragma unroll
                for (int j = 0; j < 4; ++j)
                    acc[i][j] = fmaf(a[i], b[j], acc[i][j]);
        }
    }
    #pragma unroll
    for (int i = 0; i < 8; ++i) {
        int m = m0 + ty*8 + i;
        if (m >= M) continue;
        #pragma unroll
        for (int j = 0; j < 4; ++j) {
            int n = n0 + tx*4 + j;
            if (n < N) C[(size_t)m * ldc + n] = acc[i][j];
        }
    }
}

// ---------------------------------------------------------------------------
// dt / B / C precompute -> pairs {a=exp(dt*A), u=dt*B} per (b,h,l,n), C per
// (b,l,n), padded to NPAD (pads: a=1,u=0,c=0).
// ---------------------------------------------------------------------------
__global__ __launch_bounds__(256) void dtbc_kernel(
    const float* __restrict__ dist, const float* __restrict__ zx,
    const float* __restrict__ W_bc, const float* __restrict__ W_dt,
    const float* __restrict__ dt_bias, const float* __restrict__ A_log,
    float2* __restrict__ pairs, float* __restrict__ Cc)
{
    const int r = blockIdx.x;           // b*LL + l
    const int b = r >> 11, l = r & 2047;
    const int tid = threadIdx.x;
    const float bb = zx[(size_t)r*DKEY + 1024];
    const float cb = zx[(size_t)r*DKEY + 1025];
    #pragma unroll
    for (int rep = 0; rep < 2; ++rep) {
        int n = rep*256 + tid;
        if (n >= NPAD) continue;
        if (n < NQ) {
            const float4* dp = (const float4*)(dist + ((size_t)r*NQ + n)*16);
            float d[16];
            #pragma unroll
            for (int j = 0; j < 4; ++j) {
                float4 v = dp[j];
                d[4*j+0]=v.x; d[4*j+1]=v.y; d[4*j+2]=v.z; d[4*j+3]=v.w;
            }
            float Bv = bb, Cv = cb;
            #pragma unroll
            for (int j = 0; j < 16; ++j) {
                Bv = fmaf(d[j], W_bc[j],     Bv);
                Cv = fmaf(d[j], W_bc[16+j],  Cv);
            }
            Cc[(size_t)r*NPAD + n] = Cv;
            #pragma unroll
            for (int h = 0; h < HH; ++h) {
                float s = zx[(size_t)r*DKEY + 1026 + h] + dt_bias[h];
                #pragma unroll
                for (int j = 0; j < 16; ++j) s = fmaf(d[j], W_dt[h*16+j], s);
                float dtv = (s > 20.f) ? s : log1pf(expf(s));
                float Ah = -expf(A_log[h]);
                pairs[((size_t)(b*HH+h)*LL + l)*NPAD + n] = make_float2(expf(dtv*Ah), dtv*Bv);
            }
        } else {
            Cc[(size_t)r*NPAD + n] = 0.f;
            #pragma unroll
            for (int h = 0; h < HH; ++h)
                pairs[((size_t)(b*HH+h)*LL + l)*NPAD + n] = make_float2(1.f, 0.f);
        }
    }
}

// ---------------------------------------------------------------------------
// Quarter-chunk decay products: Adec4[bh][c][q][n] = prod over 32 steps.
// Lanes cover contiguous n -> coalesced (full-line) reads despite l-stride.
// ---------------------------------------------------------------------------
__global__ __launch_bounds__(320) void adec_kernel(
    const float2* __restrict__ pairs, float* __restrict__ Adec4)
{
    const int bid = blockIdx.x;        // q + 4*(c + 16*bh)
    const int q = bid & 3, c = (bid >> 2) & 15, bh = bid >> 6;
    const int n = threadIdx.x;
    const float2* pr = pairs + ((size_t)bh*LL + c*TT + q*32)*NPAD + n;
    float prod = 1.f;
    #pragma unroll 8
    for (int t = 0; t < 32; ++t) prod *= pr[(size_t)t*NPAD].x;
    Adec4[(((size_t)bh*NCH + c)*4 + q)*NPAD + n] = prod;
}

// ---------------------------------------------------------------------------
// Sweep A: intra-chunk scan from zero state. 512 blocks = (dir,b,h,chunk),
// 512 thr. 4 sequential n-passes of 80 n (wave w owns 10 n). Coefficients
// come via 64-lane same-address vector loads (izero defeats scalarization)
// with EXPLICIT depth-1 register double-buffering; x staged in LDS.
// Block owns its y chunk exclusively -> plain +=, no extra buffers.
// ---------------------------------------------------------------------------
__global__ __launch_bounds__(512, 4) void sweepA(
    const float2* __restrict__ pairs, const float* __restrict__ Cc,
    const float* __restrict__ zx,
    float* __restrict__ Sloc, float* __restrict__ yF, float* __restrict__ yB,
    int izero)
{
    const int bid = blockIdx.x;
    const int c = bid & 15, h = (bid >> 4) & 7, b = (bid >> 7) & 1, dir = bid >> 8;
    const int tid = threadIdx.x;
    const int p = tid & 63;
    const int w = tid >> 6;
    float* __restrict__ ybuf = dir ? yB : yF;

    __shared__ float xs[TT*PP];      // 32 KB: x for the whole chunk
    __shared__ float yred[8*512];    // 16 KB

    // stage x once per block
    for (int idx = tid; idx < TT*PP; idx += 512) {
        int t = idx >> 6, pp = idx & 63;
        int ls = c*TT + t;
        int l  = dir ? (LL-1-ls) : ls;
        xs[idx] = zx[(size_t)(b*LL + l)*DKEY + 512 + h*PP + pp];
    }
    __syncthreads();

    const size_t prow = (size_t)(b*HH + h) * LL;
    const size_t crow = (size_t)b * LL;
    const size_t sbase = (((size_t)((dir*BS + b)*HH + h)*NCH + c)*NQ)*PP;

    for (int pass = 0; pass < NPASS; ++pass) {
        const int n0 = pass*80 + w*SLICE;
        const size_t zoff = (size_t)(izero * (int)tid);   // runtime 0

        float S[SLICE];
        #pragma unroll
        for (int i = 0; i < SLICE; ++i) S[i] = 0.f;

        float4 pv0[5]; float2 cv0[5];
        {   // prologue: load step 0
            int l = dir ? (LL-1 - c*TT) : c*TT;
            const float4* pr4 = (const float4*)((const float2*)(pairs + (prow + l)*NPAD + n0) + zoff);
            const float2* cw2 = (const float2*)(Cc + (crow + l)*NPAD + n0 + zoff);
            #pragma unroll
            for (int k = 0; k < 5; ++k) { pv0[k] = pr4[k]; cv0[k] = cw2[k]; }
        }

        for (int t8 = 0; t8 < NCH; ++t8) {
            #pragma unroll
            for (int tt = 0; tt < 8; ++tt) {
                const int t = t8*8 + tt;
                // prefetch t+1 (clamped at chunk end)
                float4 pv1[5]; float2 cv1[5];
                {
                    int tc = (t+1 < TT) ? t+1 : TT-1;
                    int ls = c*TT + tc;
                    int l  = dir ? (LL-1-ls) : ls;
                    const float4* pr4 = (const float4*)((const float2*)(pairs + (prow + l)*NPAD + n0) + zoff);
                    const float2* cw2 = (const float2*)(Cc + (crow + l)*NPAD + n0 + zoff);
                    #pragma unroll
                    for (int k = 0; k < 5; ++k) { pv1[k] = pr4[k]; cv1[k] = cw2[k]; }
                }
                // compute current step from registers
                const float xp = xs[(t << 6) | p];
                float yp = 0.f;
                #pragma unroll
                for (int k = 0; k < 5; ++k) {
                    float4 pv = pv0[k]; float2 cv = cv0[k];
                    S[2*k]   = fmaf(S[2*k],   pv.x, pv.y * xp);
                    yp = fmaf(S[2*k],   cv.x, yp);
                    S[2*k+1] = fmaf(S[2*k+1], pv.z, pv.w * xp);
                    yp = fmaf(S[2*k+1], cv.y, yp);
                }
                yred[tt*512 + tid] = yp;
                // rotate buffers (register renaming, no real moves)
                #pragma unroll
                for (int k = 0; k < 5; ++k) { pv0[k] = pv1[k]; cv0[k] = cv1[k]; }
            }
            __syncthreads();
            {
                int sl = tid >> 6, pp2 = tid & 63;
                float sum = 0.f;
                #pragma unroll
                for (int wv = 0; wv < 8; ++wv) sum += yred[sl*512 + wv*64 + pp2];
                int ls2 = c*TT + t8*8 + sl;
                int l2  = dir ? (LL-1-ls2) : ls2;
                size_t yi = ((size_t)(b*LL + l2)*HH + h)*PP + pp2;
                if (pass == 0) ybuf[yi] = sum; else ybuf[yi] += sum;
            }
            __syncthreads();
        }
        // chunk-end state for this pass's n-slice
        #pragma unroll
        for (int i = 0; i < SLICE; ++i) {
            int n = n0 + i;
            if (n < NQ) Sloc[sbase + (size_t)n*PP + p] = S[i];
        }
    }
}

// ---------------------------------------------------------------------------
// Inter-chunk scan: carry[c] = state before chunk c; carry[NCH] = final state.
// ---------------------------------------------------------------------------
__global__ __launch_bounds__(256) void chunkscan(
    const float* __restrict__ Sloc, const float* __restrict__ Adec4,
    const float* __restrict__ proj, float* __restrict__ carry)
{
    const int bid = blockIdx.x;          // 2400 = 32 * 75
    const int dbh = bid / 75;            // dir*16 + b*8 + h
    const int tile = bid % 75;
    const int e = tile*256 + threadIdx.x;   // < 19200
    const int n = e >> 6, p = e & 63;
    const int h = dbh & 7, b = (dbh >> 3) & 1, dir = dbh >> 4;
    const int bh = dbh & 15;
    float cur = proj[((size_t)(b*NQ + n))*DI + h*PP + p];   // init state
    const size_t cbase = (size_t)dbh * (NCH+1) * NQ * PP;
    const size_t sbase = (size_t)dbh * NCH * NQ * PP;
    carry[cbase + e] = cur;
    #pragma unroll
    for (int cc = 0; cc < NCH; ++cc) {
        int cF = dir ? (NCH-1-cc) : cc;
        const float* a4 = Adec4 + (((size_t)bh*NCH + cF)*4)*NPAD + n;
        float ad = a4[0] * a4[NPAD] * a4[2*NPAD] * a4[3*NPAD];
        cur = fmaf(cur, ad, Sloc[sbase + (size_t)cc*NQ*PP + e]);
        carry[cbase + (size_t)(cc+1)*NQ*PP + e] = cur;
    }
}

// ---------------------------------------------------------------------------
// Sweep B: y += sum_n C[l,n]*beta[l,n]*carry[n,p], beta folded into cr regs.
// Same prefetch structure as sweepA.
// ---------------------------------------------------------------------------
__global__ __launch_bounds__(512, 4) void sweepB(
    const float2* __restrict__ pairs, const float* __restrict__ Cc,
    const float* __restrict__ carry,
    float* __restrict__ yF, float* __restrict__ yB, int izero)
{
    const int bid = blockIdx.x;
    const int c = bid & 15, h = (bid >> 4) & 7, b = (bid >> 7) & 1, dir = bid >> 8;
    const int tid = threadIdx.x;
    const int p = tid & 63;
    const int w = tid >> 6;
    float* __restrict__ ybuf = dir ? yB : yF;

    __shared__ float yred[8*512];

    const size_t prow = (size_t)(b*HH + h) * LL;
    const size_t crow = (size_t)b * LL;
    const size_t cbase = (((size_t)((dir*BS + b)*HH + h)*(NCH+1) + c)*NQ)*PP;

    for (int pass = 0; pass < NPASS; ++pass) {
        const int n0 = pass*80 + w*SLICE;
        const size_t zoff = (size_t)(izero * (int)tid);

        float cr[SLICE];
        #pragma unroll
        for (int i = 0; i < SLICE; ++i) {
            int n = n0 + i;
            cr[i] = (n < NQ) ? carry[cbase + (size_t)n*PP + p] : 0.f;
        }

        float4 pv0[5]; float2 cv0[5];
        {
            int l = dir ? (LL-1 - c*TT) : c*TT;
            const float4* pr4 = (const float4*)((const float2*)(pairs + (prow + l)*NPAD + n0) + zoff);
            const float2* cw2 = (const float2*)(Cc + (crow + l)*NPAD + n0 + zoff);
            #pragma unroll
            for (int k = 0; k < 5; ++k) { pv0[k] = pr4[k]; cv0[k] = cw2[k]; }
        }

        for (int t8 = 0; t8 < NCH; ++t8) {
            #pragma unroll
            for (int tt = 0; tt < 8; ++tt) {
                const int t = t8*8 + tt;
                float4 pv1[5]; float2 cv1[5];
                {
                    int tc = (t+1 < TT) ? t+1 : TT-1;
                    int ls = c*TT + tc;
                    int l  = dir ? (LL-1-ls) : ls;
                    const float4* pr4 = (const float4*)((const float2*)(pairs + (prow + l)*NPAD + n0) + zoff);
                    const float2* cw2 = (const float2*)(Cc + (crow + l)*NPAD + n0 + zoff);
                    #pragma unroll
                    for (int k = 0; k < 5; ++k) { pv1[k] = pr4[k]; cv1[k] = cw2[k]; }
                }
                float yc = 0.f;
                #pragma unroll
                for (int k = 0; k < 5; ++k) {
                    float4 pv = pv0[k]; float2 cv = cv0[k];
                    cr[2*k]   *= pv.x;
                    yc = fmaf(cr[2*k],   cv.x, yc);
                    cr[2*k+1] *= pv.z;
                    yc = fmaf(cr[2*k+1], cv.y, yc);
                }
                yred[tt*512 + tid] = yc;
                #pragma unroll
                for (int k = 0; k < 5; ++k) { pv0[k] = pv1[k]; cv0[k] = cv1[k]; }
            }
            __syncthreads();
            {
                int sl = tid >> 6, pp2 = tid & 63;
                float sum = 0.f;
                #pragma unroll
                for (int wv = 0; wv < 8; ++wv) sum += yred[sl*512 + wv*64 + pp2];
                int ls2 = c*TT + t8*8 + sl;
                int l2  = dir ? (LL-1-ls2) : ls2;
                size_t yi = ((size_t)(b*LL + l2)*HH + h)*PP + pp2;
                ybuf[yi] += sum;
            }
            __syncthreads();
        }
    }
}

// ---------------------------------------------------------------------------
// Gated RMSNorm: g = (0.5*(yF+yB) + x*D)*silu(z); kf = g*rsqrt(mean g^2+eps)*w
// ---------------------------------------------------------------------------
__global__ __launch_bounds__(256) void gate_rms(
    const float* __restrict__ zx, const float* __restrict__ yF,
    const float* __restrict__ yB, const float* __restrict__ Dp,
    const float* __restrict__ knw, float* __restrict__ kfn)
{
    const int r = blockIdx.x, tid = threadIdx.x;
    __shared__ float part[4];
    float g[2];
    #pragma unroll
    for (int rep = 0; rep < 2; ++rep) {
        int dcol = rep*256 + tid;
        size_t yi = (size_t)r*DI + dcol;
        float zv = zx[(size_t)r*DKEY + dcol];
        float xv = zx[(size_t)r*DKEY + 512 + dcol];
        float yv = 0.5f*(yF[yi] + yB[yi]) + xv * Dp[dcol >> 6];
        float sig = 1.f / (1.f + expf(-zv));
        g[rep] = yv * (zv * sig);
    }
    float ss = g[0]*g[0] + g[1]*g[1];
    #pragma unroll
    for (int o = 32; o; o >>= 1) ss += __shfl_xor(ss, o, 64);
    if ((tid & 63) == 0) part[tid >> 6] = ss;
    __syncthreads();
    float tot = part[0] + part[1] + part[2] + part[3];
    float scale = rsqrtf(tot * (1.f/512.f) + 1e-5f);
    #pragma unroll
    for (int rep = 0; rep < 2; ++rep) {
        int dcol = rep*256 + tid;
        kfn[(size_t)r*DI + dcol] = g[rep] * scale * knw[dcol];
    }
}

// ---------------------------------------------------------------------------
// Final-state LayerNorm: lastn[b,q,(h,p)] from 0.5*(Sf+Sb)
// ---------------------------------------------------------------------------
__global__ __launch_bounds__(512) void state_ln(
    const float* __restrict__ carry, const float* __restrict__ qw,
    const float* __restrict__ qb, float* __restrict__ lastn)
{
    const int row = blockIdx.x;          // b*NQ + q
    const int b = row / NQ, q = row % NQ;
    const int tid = threadIdx.x;         // 512
    const int h = tid >> 6, p = tid & 63;
    __shared__ float pm[8], pv[8];
    size_t iF = ((((size_t)((0*BS + b)*HH + h))*(NCH+1) + NCH)*NQ + q)*PP + p;
    size_t iB = ((((size_t)((1*BS + b)*HH + h))*(NCH+1) + NCH)*NQ + q)*PP + p;
    float v = 0.5f * (carry[iF] + carry[iB]);
    float s1 = v, s2 = v*v;
    #pragma unroll
    for (int o = 32; o; o >>= 1) { s1 += __shfl_xor(s1, o, 64); s2 += __shfl_xor(s2, o, 64); }
    if ((tid & 63) == 0) { pm[tid >> 6] = s1; pv[tid >> 6] = s2; }
    __syncthreads();
    float m = 0.f, s = 0.f;
    #pragma unroll
    for (int i = 0; i < 8; ++i) { m += pm[i]; s += pv[i]; }
    m *= (1.f/512.f);
    s = s*(1.f/512.f) - m*m;
    lastn[(size_t)row*DI + tid] = (v - m)*rsqrtf(s + 1e-5f)*qw[tid] + qb[tid];
}

// ---------------------------------------------------------------------------
extern "C" void kernel_launch(void* const* d_in, const int* in_sizes, int n_in,
                              void* d_out, int out_size, void* d_ws, size_t ws_size,
                              hipStream_t stream)
{
    const float* in_key    = (const float*)d_in[0];
    const float* in_query  = (const float*)d_in[1];
    const float* dist      = (const float*)d_in[2];
    const float* W_key     = (const float*)d_in[3];
    const float* W_query   = (const float*)d_in[4];
    const float* W_bc      = (const float*)d_in[5];
    const float* W_dt      = (const float*)d_in[6];
    const float* dt_bias   = (const float*)d_in[7];
    const float* A_log     = (const float*)d_in[8];
    const float* Dp        = (const float*)d_in[9];
    const float* W_out_key = (const float*)d_in[10];
    const float* W_out_qry = (const float*)d_in[11];
    const float* knw       = (const float*)d_in[12];
    const float* qw        = (const float*)d_in[13];
    const float* qb        = (const float*)d_in[14];
    float* out = (float*)d_out;

    float* ws = (float*)d_ws;
    size_t off = 0;
    auto alloc = [&](size_t nf) { float* pp = ws + off; off += nf; return pp; };
    float*  zx    = alloc((size_t)4096*DKEY);             // 4.24M
    float*  proj  = alloc((size_t)600*DI);                // 0.31M
    float2* pairs = (float2*)alloc((size_t)16*LL*NPAD*2); // 21.0M floats
    float*  Cc    = alloc((size_t)BS*LL*NPAD);            // 1.31M
    float*  Sloc  = alloc((size_t)32*NCH*NQ*PP);          // 9.83M (reused for kfn/lastn)
    float*  Adec4 = alloc((size_t)16*NCH*4*NPAD);         // 0.33M
    float*  carry = alloc((size_t)32*(NCH+1)*NQ*PP);      // 10.4M
    float*  yF    = alloc((size_t)BS*LL*DI);              // 2.1M
    float*  yB    = alloc((size_t)BS*LL*DI);              // 2.1M
    float*  kfn   = Sloc;                                  // alias (dead after chunkscan)
    float*  lastn = Sloc + (size_t)4096*DI;
    if (off * sizeof(float) > ws_size) {
        fprintf(stderr, "kernel_launch: workspace too small: need %zu bytes, have %zu\n",
                off * sizeof(float), ws_size);
        return;
    }

    dim3 blk(256);
    // K1: zxbcdt = in_key @ W_key^T   [4096 x 1034]
    gemm_nt_big<<<dim3(32, 17), blk, 0, stream>>>(in_key, W_key, zx, 4096, DKEY, 256, 256, 256, DKEY);
    // K2: init = in_query @ W_query^T  [600 x 512]
    gemm_nt<<<dim3(10, 8), blk, 0, stream>>>(in_query, W_query, proj, 600, DI, 256, 256, 256, DI);
    // K3: coefficient precompute
    dtbc_kernel<<<4096, blk, 0, stream>>>(dist, zx, W_bc, W_dt, dt_bias, A_log, pairs, Cc);
    // K3b: quarter-chunk decay products (dir-shared)
    adec_kernel<<<1024, dim3(320), 0, stream>>>(pairs, Adec4);
    // K4: intra-chunk scans (both directions; 4 sequential n-passes in-block)
    sweepA<<<512, dim3(512), 0, stream>>>(pairs, Cc, zx, Sloc, yF, yB, 0);
    // K5: inter-chunk scan
    chunkscan<<<2400, blk, 0, stream>>>(Sloc, Adec4, proj, carry);
    // K6: carry corrections into y
    sweepB<<<512, dim3(512), 0, stream>>>(pairs, Cc, carry, yF, yB, 0);
    // K7: gated RMSNorm + out_key projection
    gate_rms<<<4096, blk, 0, stream>>>(zx, yF, yB, Dp, knw, kfn);
    gemm_nt<<<dim3(64, 4), blk, 0, stream>>>(kfn, W_out_key, out, 4096, 256, DI, DI, DI, 256);
    // K8: final-state LayerNorm + out_query projection
    state_ln<<<600, dim3(512), 0, stream>>>(carry, qw, qb, lastn);
    gemm_nt<<<dim3(10, 4), blk, 0, stream>>>(lastn, W_out_qry, out + (size_t)4096*256, 600, 256, DI, DI, DI, 256);
}

// Round 6
// 591.611 us; speedup vs baseline: 2.1726x; 2.0869x over previous
//
#include <hip/hip_runtime.h>
#include <hip/hip_bf16.h>
#include <cstdio>

// Problem dims
#define BS   2
#define LL   2048
#define HH   8
#define PP   64
#define NQ   300          // d_state / num queries
#define NPAD 320          // padded n
#define NG   5            // n-groups of 64 lanes (5*64 = 320)
#define PJ   8            // p's per wave (8 waves * 8 = 64 = PP)
#define TT   128          // chunk length
#define NCH  16           // L / TT
#define DI   512
#define DKEY 1034

// ---------------------------------------------------------------------------
// Generic GEMM-NT: C[m,n] = sum_k A[m*lda+k] * B[n*ldb+k]  (64x64 tile)
// ---------------------------------------------------------------------------
__global__ __launch_bounds__(256) void gemm_nt(
    const float* __restrict__ A, const float* __restrict__ Bm, float* __restrict__ C,
    int M, int N, int K, int lda, int ldb, int ldc)
{
    __shared__ float As[16][68];
    __shared__ float Bs[16][68];
    const int tid = threadIdx.x;
    const int tx = tid & 15, ty = tid >> 4;
    const int m0 = blockIdx.x * 64, n0 = blockIdx.y * 64;
    const int lr = tid >> 2, lk = (tid & 3) << 2;
    float acc[4][4] = {};
    for (int k0 = 0; k0 < K; k0 += 16) {
        float4 av = make_float4(0.f,0.f,0.f,0.f), bv = make_float4(0.f,0.f,0.f,0.f);
        int am = m0 + lr;
        if (am < M) av = *(const float4*)(A + (size_t)am * lda + k0 + lk);
        int bn = n0 + lr;
        if (bn < N) bv = *(const float4*)(Bm + (size_t)bn * ldb + k0 + lk);
        __syncthreads();
        As[lk+0][lr] = av.x; As[lk+1][lr] = av.y; As[lk+2][lr] = av.z; As[lk+3][lr] = av.w;
        Bs[lk+0][lr] = bv.x; Bs[lk+1][lr] = bv.y; Bs[lk+2][lr] = bv.z; Bs[lk+3][lr] = bv.w;
        __syncthreads();
        #pragma unroll
        for (int kk = 0; kk < 16; ++kk) {
            float a0 = As[kk][ty*4+0], a1 = As[kk][ty*4+1], a2 = As[kk][ty*4+2], a3 = As[kk][ty*4+3];
            float b0 = Bs[kk][tx*4+0], b1 = Bs[kk][tx*4+1], b2 = Bs[kk][tx*4+2], b3 = Bs[kk][tx*4+3];
            acc[0][0] = fmaf(a0,b0,acc[0][0]); acc[0][1] = fmaf(a0,b1,acc[0][1]);
            acc[0][2] = fmaf(a0,b2,acc[0][2]); acc[0][3] = fmaf(a0,b3,acc[0][3]);
            acc[1][0] = fmaf(a1,b0,acc[1][0]); acc[1][1] = fmaf(a1,b1,acc[1][1]);
            acc[1][2] = fmaf(a1,b2,acc[1][2]); acc[1][3] = fmaf(a1,b3,acc[1][3]);
            acc[2][0] = fmaf(a2,b0,acc[2][0]); acc[2][1] = fmaf(a2,b1,acc[2][1]);
            acc[2][2] = fmaf(a2,b2,acc[2][2]); acc[2][3] = fmaf(a2,b3,acc[2][3]);
            acc[3][0] = fmaf(a3,b0,acc[3][0]); acc[3][1] = fmaf(a3,b1,acc[3][1]);
            acc[3][2] = fmaf(a3,b2,acc[3][2]); acc[3][3] = fmaf(a3,b3,acc[3][3]);
        }
    }
    #pragma unroll
    for (int i = 0; i < 4; ++i) {
        int m = m0 + ty*4 + i;
        if (m >= M) continue;
        #pragma unroll
        for (int j = 0; j < 4; ++j) {
            int n = n0 + tx*4 + j;
            if (n < N) C[(size_t)m * ldc + n] = acc[i][j];
        }
    }
}

// ---------------------------------------------------------------------------
// Bigger GEMM-NT: 128x64 tile, 256 threads, 8x4 micro-tile.
// ---------------------------------------------------------------------------
__global__ __launch_bounds__(256) void gemm_nt_big(
    const float* __restrict__ A, const float* __restrict__ Bm, float* __restrict__ C,
    int M, int N, int K, int lda, int ldb, int ldc)
{
    __shared__ float As[16][132];
    __shared__ float Bs[16][68];
    const int tid = threadIdx.x;
    const int tx = tid & 15, ty = tid >> 4;
    const int m0 = blockIdx.x * 128, n0 = blockIdx.y * 64;
    const int lr = tid >> 2, lk = (tid & 3) << 2;
    float acc[8][4] = {};
    for (int k0 = 0; k0 < K; k0 += 16) {
        float4 a0v = make_float4(0.f,0.f,0.f,0.f), a1v = a0v, bv = a0v;
        int am0 = m0 + lr, am1 = m0 + 64 + lr;
        if (am0 < M) a0v = *(const float4*)(A + (size_t)am0 * lda + k0 + lk);
        if (am1 < M) a1v = *(const float4*)(A + (size_t)am1 * lda + k0 + lk);
        int bn = n0 + lr;
        if (bn < N) bv = *(const float4*)(Bm + (size_t)bn * ldb + k0 + lk);
        __syncthreads();
        As[lk+0][lr] = a0v.x; As[lk+1][lr] = a0v.y; As[lk+2][lr] = a0v.z; As[lk+3][lr] = a0v.w;
        As[lk+0][64+lr] = a1v.x; As[lk+1][64+lr] = a1v.y; As[lk+2][64+lr] = a1v.z; As[lk+3][64+lr] = a1v.w;
        Bs[lk+0][lr] = bv.x; Bs[lk+1][lr] = bv.y; Bs[lk+2][lr] = bv.z; Bs[lk+3][lr] = bv.w;
        __syncthreads();
        #pragma unroll
        for (int kk = 0; kk < 16; ++kk) {
            float a[8], b[4];
            #pragma unroll
            for (int i = 0; i < 8; ++i) a[i] = As[kk][ty*8+i];
            #pragma unroll
            for (int j = 0; j < 4; ++j) b[j] = Bs[kk][tx*4+j];
            #pragma unroll
            for (int i = 0; i < 8; ++i)
                #pragma unroll
                for (int j = 0; j < 4; ++j)
                    acc[i][j] = fmaf(a[i], b[j], acc[i][j]);
        }
    }
    #pragma unroll
    for (int i = 0; i < 8; ++i) {
        int m = m0 + ty*8 + i;
        if (m >= M) continue;
        #pragma unroll
        for (int j = 0; j < 4; ++j) {
            int n = n0 + tx*4 + j;
            if (n < N) C[(size_t)m * ldc + n] = acc[i][j];
        }
    }
}

// ---------------------------------------------------------------------------
// dt / B / C precompute -> pairs {a=exp(dt*A), u=dt*B} per (b,h,l,n), C per
// (b,l,n), padded to NPAD (pads: a=1,u=0,c=0).
// ---------------------------------------------------------------------------
__global__ __launch_bounds__(256) void dtbc_kernel(
    const float* __restrict__ dist, const float* __restrict__ zx,
    const float* __restrict__ W_bc, const float* __restrict__ W_dt,
    const float* __restrict__ dt_bias, const float* __restrict__ A_log,
    float2* __restrict__ pairs, float* __restrict__ Cc)
{
    const int r = blockIdx.x;           // b*LL + l
    const int b = r >> 11, l = r & 2047;
    const int tid = threadIdx.x;
    const float bb = zx[(size_t)r*DKEY + 1024];
    const float cb = zx[(size_t)r*DKEY + 1025];
    #pragma unroll
    for (int rep = 0; rep < 2; ++rep) {
        int n = rep*256 + tid;
        if (n >= NPAD) continue;
        if (n < NQ) {
            const float4* dp = (const float4*)(dist + ((size_t)r*NQ + n)*16);
            float d[16];
            #pragma unroll
            for (int j = 0; j < 4; ++j) {
                float4 v = dp[j];
                d[4*j+0]=v.x; d[4*j+1]=v.y; d[4*j+2]=v.z; d[4*j+3]=v.w;
            }
            float Bv = bb, Cv = cb;
            #pragma unroll
            for (int j = 0; j < 16; ++j) {
                Bv = fmaf(d[j], W_bc[j],     Bv);
                Cv = fmaf(d[j], W_bc[16+j],  Cv);
            }
            Cc[(size_t)r*NPAD + n] = Cv;
            #pragma unroll
            for (int h = 0; h < HH; ++h) {
                float s = zx[(size_t)r*DKEY + 1026 + h] + dt_bias[h];
                #pragma unroll
                for (int j = 0; j < 16; ++j) s = fmaf(d[j], W_dt[h*16+j], s);
                float dtv = (s > 20.f) ? s : log1pf(expf(s));
                float Ah = -expf(A_log[h]);
                pairs[((size_t)(b*HH+h)*LL + l)*NPAD + n] = make_float2(expf(dtv*Ah), dtv*Bv);
            }
        } else {
            Cc[(size_t)r*NPAD + n] = 0.f;
            #pragma unroll
            for (int h = 0; h < HH; ++h)
                pairs[((size_t)(b*HH+h)*LL + l)*NPAD + n] = make_float2(1.f, 0.f);
        }
    }
}

// ---------------------------------------------------------------------------
// Quarter-chunk decay products: Adec4[bh][c][q][n] = prod over 32 steps.
// ---------------------------------------------------------------------------
__global__ __launch_bounds__(320) void adec_kernel(
    const float2* __restrict__ pairs, float* __restrict__ Adec4)
{
    const int bid = blockIdx.x;        // q + 4*(c + 16*bh)
    const int q = bid & 3, c = (bid >> 2) & 15, bh = bid >> 6;
    const int n = threadIdx.x;
    const float2* pr = pairs + ((size_t)bh*LL + c*TT + q*32)*NPAD + n;
    float prod = 1.f;
    #pragma unroll 8
    for (int t = 0; t < 32; ++t) prod *= pr[(size_t)t*NPAD].x;
    Adec4[(((size_t)bh*NCH + c)*4 + q)*NPAD + n] = prod;
}

// ---------------------------------------------------------------------------
// Transpose init states: projT[(b*8+h)*64+p][n] = proj[b*NQ+n][h*64+p] (0-pad)
// ---------------------------------------------------------------------------
__global__ __launch_bounds__(320) void transpose_proj(
    const float* __restrict__ proj, float* __restrict__ projT)
{
    const int bid = blockIdx.x;       // (b*8+h)*64 + p
    const int p = bid & 63, h = (bid >> 6) & 7, b = bid >> 9;
    const int n = threadIdx.x;
    float v = 0.f;
    if (n < NQ) v = proj[((size_t)(b*NQ + n))*DI + h*64 + p];
    projT[(size_t)bid*NPAD + n] = v;
}

// ---------------------------------------------------------------------------
// 64-lane reduce-scatter: input yl[8] per lane, output: lane L holds the
// 64-lane sum of index j = L&7. 7 shuffles + ~27 VALU.
// ---------------------------------------------------------------------------
__device__ __forceinline__ float reduce8x64(const float yl[8], int L)
{
    const bool h1 = (L & 1), h2 = (L & 2), h4 = (L & 4);
    float t0 = (h1 ? yl[1] : yl[0]) + __shfl_xor(h1 ? yl[0] : yl[1], 1, 64);
    float t1 = (h1 ? yl[3] : yl[2]) + __shfl_xor(h1 ? yl[2] : yl[3], 1, 64);
    float t2 = (h1 ? yl[5] : yl[4]) + __shfl_xor(h1 ? yl[4] : yl[5], 1, 64);
    float t3 = (h1 ? yl[7] : yl[6]) + __shfl_xor(h1 ? yl[6] : yl[7], 1, 64);
    float u0 = (h2 ? t1 : t0) + __shfl_xor(h2 ? t0 : t1, 2, 64);
    float u1 = (h2 ? t3 : t2) + __shfl_xor(h2 ? t2 : t3, 2, 64);
    float v  = (h4 ? u1 : u0) + __shfl_xor(h4 ? u0 : u1, 4, 64);
    v += __shfl_xor(v, 8, 64);
    v += __shfl_xor(v, 16, 64);
    v += __shfl_xor(v, 32, 64);
    return v;
}

// ---------------------------------------------------------------------------
// Sweep A: intra-chunk scan, lane = n (coalesced coefficient loads!).
// 512 blocks = (dir,b,h,chunk), 512 thr. Wave w owns p in [w*8, w*8+8)
// (register dim), all lanes cover one 64-n group x NG groups in registers.
// x[t][p] staged to LDS once; per step: 10 coalesced loads + 2 LDS broadcast
// reads + 120 FMA + reduce-scatter. Waves fully independent (no barriers).
// ---------------------------------------------------------------------------
__global__ __launch_bounds__(512, 4) void sweepA(
    const float2* __restrict__ pairs, const float* __restrict__ Cc,
    const float* __restrict__ zx,
    float* __restrict__ Sloc, float* __restrict__ yFa, float* __restrict__ yBa)
{
    const int bid = blockIdx.x;
    const int c = bid & 15, h = (bid >> 4) & 7, b = (bid >> 7) & 1, dir = bid >> 8;
    const int tid = threadIdx.x;
    const int L = tid & 63, w = tid >> 6;
    float* __restrict__ ybuf = dir ? yBa : yFa;

    __shared__ float xs[TT*64];      // 32 KB: x[t][p] for the whole chunk

    for (int idx = tid; idx < TT*64; idx += 512) {
        int t = idx >> 6, pp = idx & 63;
        int ls = c*TT + t;
        int l = dir ? (LL-1-ls) : ls;
        xs[idx] = zx[(size_t)(b*LL + l)*DKEY + 512 + h*64 + pp];
    }
    __syncthreads();

    const int lstart = dir ? (LL-1 - c*TT) : c*TT;
    const int lstep  = dir ? -1 : 1;
    const float2* __restrict__ pb = pairs + ((size_t)(b*HH+h)*LL + lstart)*NPAD + L;
    const float*  __restrict__ cb = Cc + ((size_t)(b*LL) + lstart)*NPAD + L;
    const ptrdiff_t pstride = (ptrdiff_t)lstep * NPAD;

    float S[NG][PJ];
    #pragma unroll
    for (int g = 0; g < NG; ++g)
        #pragma unroll
        for (int j = 0; j < PJ; ++j) S[g][j] = 0.f;

    float2 pv[2][NG]; float cv[2][NG];
    #pragma unroll
    for (int g = 0; g < NG; ++g) { pv[0][g] = pb[g*64]; cv[0][g] = cb[g*64]; }

    for (int t8 = 0; t8 < TT/8; ++t8) {
        #pragma unroll
        for (int tt = 0; tt < 8; ++tt) {
            const int t = t8*8 + tt;
            const int cur = tt & 1, nxt = cur ^ 1;
            const int tn = (t+1 < TT) ? t+1 : t;
            const float2* pn = pb + (ptrdiff_t)tn * pstride;
            const float*  cn = cb + (ptrdiff_t)tn * pstride;
            #pragma unroll
            for (int g = 0; g < NG; ++g) { pv[nxt][g] = pn[g*64]; cv[nxt][g] = cn[g*64]; }

            const float4* xp = (const float4*)&xs[(t << 6) + w*PJ];
            float4 xa = xp[0], xb2 = xp[1];
            float xv[8] = {xa.x, xa.y, xa.z, xa.w, xb2.x, xb2.y, xb2.z, xb2.w};

            float yl[8];
            #pragma unroll
            for (int j = 0; j < 8; ++j) yl[j] = 0.f;
            #pragma unroll
            for (int g = 0; g < NG; ++g) {
                const float a = pv[cur][g].x, u = pv[cur][g].y, cg = cv[cur][g];
                #pragma unroll
                for (int j = 0; j < PJ; ++j) {
                    S[g][j] = fmaf(S[g][j], a, u * xv[j]);
                    yl[j] = fmaf(S[g][j], cg, yl[j]);
                }
            }
            float v = reduce8x64(yl, L);
            if (L < 8) {
                int l = lstart + t*lstep;
                ybuf[(((size_t)(b*LL + l))*HH + h)*64 + w*PJ + L] = v;
            }
        }
    }
    // chunk-end state: Sloc[dbh][c][p][n]
    const int dbh = dir*16 + b*8 + h;
    const size_t sb = (((size_t)dbh*NCH + c)*64)*NPAD;
    #pragma unroll
    for (int g = 0; g < NG; ++g)
        #pragma unroll
        for (int j = 0; j < PJ; ++j)
            Sloc[sb + (size_t)(w*PJ + j)*NPAD + g*64 + L] = S[g][j];
}

// ---------------------------------------------------------------------------
// Inter-chunk scan over [p][n] layout: block = (dbh, p), lane = n.
// carry[dbh][c][p][n]: state before chunk c; c=NCH is the final state.
// ---------------------------------------------------------------------------
__global__ __launch_bounds__(320) void chunkscan(
    const float* __restrict__ Sloc, const float* __restrict__ Adec4,
    const float* __restrict__ projT, float* __restrict__ carry)
{
    const int bid = blockIdx.x;      // dbh*64 + p
    const int p = bid & 63, dbh = bid >> 6;
    const int bh = dbh & 15, dir = dbh >> 4;
    const int n = threadIdx.x;
    float cur = projT[(size_t)(bh*64 + p)*NPAD + n];
    carry[((size_t)(dbh*(NCH+1) + 0)*64 + p)*NPAD + n] = cur;
    #pragma unroll
    for (int cc = 0; cc < NCH; ++cc) {
        int cF = dir ? (NCH-1-cc) : cc;
        const float* a4 = Adec4 + ((size_t)(bh*NCH + cF)*4)*NPAD + n;
        float ad = a4[0]*a4[NPAD]*a4[2*NPAD]*a4[3*NPAD];
        cur = fmaf(cur, ad, Sloc[((size_t)(dbh*NCH + cc)*64 + p)*NPAD + n]);
        carry[((size_t)(dbh*(NCH+1) + cc + 1)*64 + p)*NPAD + n] = cur;
    }
}

// ---------------------------------------------------------------------------
// Sweep B: carry corrections, same lane=n structure as sweepA.
// cr[g][j] *= a each step; y += cr*C; writes its own partial buffers.
// ---------------------------------------------------------------------------
__global__ __launch_bounds__(512, 4) void sweepB(
    const float2* __restrict__ pairs, const float* __restrict__ Cc,
    const float* __restrict__ carry,
    float* __restrict__ yFb, float* __restrict__ yBb)
{
    const int bid = blockIdx.x;
    const int c = bid & 15, h = (bid >> 4) & 7, b = (bid >> 7) & 1, dir = bid >> 8;
    const int tid = threadIdx.x;
    const int L = tid & 63, w = tid >> 6;
    float* __restrict__ ybuf = dir ? yBb : yFb;

    const int dbh = dir*16 + b*8 + h;
    const size_t cb0 = ((size_t)(dbh*(NCH+1) + c)*64)*NPAD;
    float cr[NG][PJ];
    #pragma unroll
    for (int g = 0; g < NG; ++g)
        #pragma unroll
        for (int j = 0; j < PJ; ++j)
            cr[g][j] = carry[cb0 + (size_t)(w*PJ + j)*NPAD + g*64 + L];

    const int lstart = dir ? (LL-1 - c*TT) : c*TT;
    const int lstep  = dir ? -1 : 1;
    const float2* __restrict__ pb = pairs + ((size_t)(b*HH+h)*LL + lstart)*NPAD + L;
    const float*  __restrict__ cb = Cc + ((size_t)(b*LL) + lstart)*NPAD + L;
    const ptrdiff_t pstride = (ptrdiff_t)lstep * NPAD;

    float2 pv[2][NG]; float cv[2][NG];
    #pragma unroll
    for (int g = 0; g < NG; ++g) { pv[0][g] = pb[g*64]; cv[0][g] = cb[g*64]; }

    for (int t8 = 0; t8 < TT/8; ++t8) {
        #pragma unroll
        for (int tt = 0; tt < 8; ++tt) {
            const int t = t8*8 + tt;
            const int cur = tt & 1, nxt = cur ^ 1;
            const int tn = (t+1 < TT) ? t+1 : t;
            const float2* pn = pb + (ptrdiff_t)tn * pstride;
            const float*  cn = cb + (ptrdiff_t)tn * pstride;
            #pragma unroll
            for (int g = 0; g < NG; ++g) { pv[nxt][g] = pn[g*64]; cv[nxt][g] = cn[g*64]; }

            float yl[8];
            #pragma unroll
            for (int j = 0; j < 8; ++j) yl[j] = 0.f;
            #pragma unroll
            for (int g = 0; g < NG; ++g) {
                const float a = pv[cur][g].x, cg = cv[cur][g];
                #pragma unroll
                for (int j = 0; j < PJ; ++j) {
                    cr[g][j] *= a;
                    yl[j] = fmaf(cr[g][j], cg, yl[j]);
                }
            }
            float v = reduce8x64(yl, L);
            if (L < 8) {
                int l = lstart + t*lstep;
                ybuf[(((size_t)(b*LL + l))*HH + h)*64 + w*PJ + L] = v;
            }
        }
    }
}

// ---------------------------------------------------------------------------
// Gated RMSNorm: g = (0.5*(yFa+yBa+yFb+yBb) + x*D)*silu(z)
// ---------------------------------------------------------------------------
__global__ __launch_bounds__(256) void gate_rms(
    const float* __restrict__ zx,
    const float* __restrict__ yFa, const float* __restrict__ yBa,
    const float* __restrict__ yFb, const float* __restrict__ yBb,
    const float* __restrict__ Dp,
    const float* __restrict__ knw, float* __restrict__ kfn)
{
    const int r = blockIdx.x, tid = threadIdx.x;
    __shared__ float part[4];
    float g[2];
    #pragma unroll
    for (int rep = 0; rep < 2; ++rep) {
        int dcol = rep*256 + tid;
        size_t yi = (size_t)r*DI + dcol;
        float zv = zx[(size_t)r*DKEY + dcol];
        float xv = zx[(size_t)r*DKEY + 512 + dcol];
        float yv = 0.5f*(yFa[yi] + yBa[yi] + yFb[yi] + yBb[yi]) + xv * Dp[dcol >> 6];
        float sig = 1.f / (1.f + expf(-zv));
        g[rep] = yv * (zv * sig);
    }
    float ss = g[0]*g[0] + g[1]*g[1];
    #pragma unroll
    for (int o = 32; o; o >>= 1) ss += __shfl_xor(ss, o, 64);
    if ((tid & 63) == 0) part[tid >> 6] = ss;
    __syncthreads();
    float tot = part[0] + part[1] + part[2] + part[3];
    float scale = rsqrtf(tot * (1.f/512.f) + 1e-5f);
    #pragma unroll
    for (int rep = 0; rep < 2; ++rep) {
        int dcol = rep*256 + tid;
        kfn[(size_t)r*DI + dcol] = g[rep] * scale * knw[dcol];
    }
}

// ---------------------------------------------------------------------------
// Final-state LayerNorm from carry[dbh][NCH][p][q] (fwd+bwd averaged)
// ---------------------------------------------------------------------------
__global__ __launch_bounds__(512) void state_ln(
    const float* __restrict__ carry, const float* __restrict__ qw,
    const float* __restrict__ qb, float* __restrict__ lastn)
{
    const int row = blockIdx.x;          // b*NQ + q
    const int b = row / NQ, q = row % NQ;
    const int tid = threadIdx.x;         // 512
    const int h = tid >> 6, p = tid & 63;
    __shared__ float pm[8], pv[8];
    size_t iF = ((size_t)((0*16 + b*8 + h)*(NCH+1) + NCH)*64 + p)*NPAD + q;
    size_t iB = ((size_t)((16   + b*8 + h)*(NCH+1) + NCH)*64 + p)*NPAD + q;
    float v = 0.5f * (carry[iF] + carry[iB]);
    float s1 = v, s2 = v*v;
    #pragma unroll
    for (int o = 32; o; o >>= 1) { s1 += __shfl_xor(s1, o, 64); s2 += __shfl_xor(s2, o, 64); }
    if ((tid & 63) == 0) { pm[tid >> 6] = s1; pv[tid >> 6] = s2; }
    __syncthreads();
    float m = 0.f, s = 0.f;
    #pragma unroll
    for (int i = 0; i < 8; ++i) { m += pm[i]; s += pv[i]; }
    m *= (1.f/512.f);
    s = s*(1.f/512.f) - m*m;
    lastn[(size_t)row*DI + tid] = (v - m)*rsqrtf(s + 1e-5f)*qw[tid] + qb[tid];
}

// ---------------------------------------------------------------------------
extern "C" void kernel_launch(void* const* d_in, const int* in_sizes, int n_in,
                              void* d_out, int out_size, void* d_ws, size_t ws_size,
                              hipStream_t stream)
{
    const float* in_key    = (const float*)d_in[0];
    const float* in_query  = (const float*)d_in[1];
    const float* dist      = (const float*)d_in[2];
    const float* W_key     = (const float*)d_in[3];
    const float* W_query   = (const float*)d_in[4];
    const float* W_bc      = (const float*)d_in[5];
    const float* W_dt      = (const float*)d_in[6];
    const float* dt_bias   = (const float*)d_in[7];
    const float* A_log     = (const float*)d_in[8];
    const float* Dp        = (const float*)d_in[9];
    const float* W_out_key = (const float*)d_in[10];
    const float* W_out_qry = (const float*)d_in[11];
    const float* knw       = (const float*)d_in[12];
    const float* qw        = (const float*)d_in[13];
    const float* qb        = (const float*)d_in[14];
    float* out = (float*)d_out;

    float* ws = (float*)d_ws;
    size_t off = 0;
    auto alloc = [&](size_t nf) { float* pp = ws + off; off += nf; return pp; };
    float*  zx    = alloc((size_t)4096*DKEY);             // 4.24M
    float*  proj  = alloc((size_t)600*DI);                // 0.31M
    float*  projT = alloc((size_t)1024*NPAD);             // 0.33M
    float2* pairs = (float2*)alloc((size_t)16*LL*NPAD*2); // 21.0M floats
    float*  Cc    = alloc((size_t)BS*LL*NPAD);            // 1.31M
    float*  Sloc  = alloc((size_t)32*NCH*64*NPAD);        // 10.5M (reused later)
    float*  Adec4 = alloc((size_t)16*NCH*4*NPAD);         // 0.33M
    float*  carry = alloc((size_t)32*(NCH+1)*64*NPAD);    // 11.1M
    float*  yFa   = alloc((size_t)BS*LL*DI);              // 2.1M
    float*  yBa   = alloc((size_t)BS*LL*DI);              // 2.1M
    // aliased into Sloc (dead after chunkscan):
    float*  yFb   = Sloc;
    float*  yBb   = Sloc + (size_t)BS*LL*DI;
    float*  kfn   = Sloc + (size_t)2*BS*LL*DI;
    float*  lastn = Sloc + (size_t)3*BS*LL*DI;
    if (off * sizeof(float) > ws_size) {
        fprintf(stderr, "kernel_launch: workspace too small: need %zu bytes, have %zu\n",
                off * sizeof(float), ws_size);
        return;
    }

    dim3 blk(256);
    // K1: zxbcdt = in_key @ W_key^T   [4096 x 1034]
    gemm_nt_big<<<dim3(32, 17), blk, 0, stream>>>(in_key, W_key, zx, 4096, DKEY, 256, 256, 256, DKEY);
    // K2: init = in_query @ W_query^T  [600 x 512] + transpose
    gemm_nt<<<dim3(10, 8), blk, 0, stream>>>(in_query, W_query, proj, 600, DI, 256, 256, 256, DI);
    transpose_proj<<<1024, dim3(320), 0, stream>>>(proj, projT);
    // K3: coefficient precompute
    dtbc_kernel<<<4096, blk, 0, stream>>>(dist, zx, W_bc, W_dt, dt_bias, A_log, pairs, Cc);
    // K3b: quarter-chunk decay products (dir-shared)
    adec_kernel<<<1024, dim3(320), 0, stream>>>(pairs, Adec4);
    // K4: intra-chunk scans (lane = n, coalesced coefficient streams)
    sweepA<<<512, dim3(512), 0, stream>>>(pairs, Cc, zx, Sloc, yFa, yBa);
    // K5: inter-chunk scan
    chunkscan<<<2048, dim3(320), 0, stream>>>(Sloc, Adec4, projT, carry);
    // K6: carry corrections into y
    sweepB<<<512, dim3(512), 0, stream>>>(pairs, Cc, carry, yFb, yBb);
    // K7: gated RMSNorm + out_key projection
    gate_rms<<<4096, blk, 0, stream>>>(zx, yFa, yBa, yFb, yBb, Dp, knw, kfn);
    gemm_nt<<<dim3(64, 4), blk, 0, stream>>>(kfn, W_out_key, out, 4096, 256, DI, DI, DI, 256);
    // K8: final-state LayerNorm + out_query projection
    state_ln<<<600, dim3(512), 0, stream>>>(carry, qw, qb, lastn);
    gemm_nt<<<dim3(10, 4), blk, 0, stream>>>(lastn, W_out_qry, out + (size_t)4096*256, 600, 256, DI, DI, DI, 256);
}